// Round 1
// baseline (288.892 us; speedup 1.0000x reference)
//
#include <hip/hip_runtime.h>
#include <stdint.h>
#include <math.h>

#define B_DIM 2048
#define M_DIM 512
#define E_DIM 8
#define K_TOP 10
#define NUM_MC 25
#define NWAVES (B_DIM * NUM_MC) /* 51200 waves, one per (b, mc-sample) */
#define WPB 4                   /* waves per block (256 threads) */

#define RK0 0xA341316Cu
#define RK1 0xC8013EA4u

__device__ __forceinline__ uint32_t rotl32(uint32_t x, int r) {
  return (x << r) | (x >> (32 - r));
}

// Standard threefry-2x32, 20 rounds. Counter-based PRF: (x0,x1) -> (o0,o1).
__device__ __forceinline__ void tf2x32(uint32_t k0, uint32_t k1,
                                       uint32_t x0, uint32_t x1,
                                       uint32_t& o0, uint32_t& o1) {
  const uint32_t k2 = k0 ^ k1 ^ 0x1BD11BDAu;
  x0 += k0; x1 += k1;
#define TF_R(r) { x0 += x1; x1 = rotl32(x1, (r)); x1 ^= x0; }
  TF_R(13) TF_R(15) TF_R(26) TF_R(6)
  x0 += k1; x1 += k2 + 1u;
  TF_R(17) TF_R(29) TF_R(16) TF_R(24)
  x0 += k2; x1 += k0 + 2u;
  TF_R(13) TF_R(15) TF_R(26) TF_R(6)
  x0 += k0; x1 += k1 + 3u;
  TF_R(17) TF_R(29) TF_R(16) TF_R(24)
  x0 += k1; x1 += k2 + 4u;
  TF_R(13) TF_R(15) TF_R(26) TF_R(6)
  x0 += k2; x1 += k0 + 5u;
#undef TF_R
  o0 = x0; o1 = x1;
}

// bits -> u in [tiny, 1) on the same 2^-23 grid JAX uses, then standard Gumbel.
__device__ __forceinline__ float gumbel_from_bits(uint32_t bits) {
  float u = __uint_as_float(0x3f800000u | (bits >> 9)) - 1.0f;
  u = fmaxf(u, 1.17549435e-38f);
  return -__logf(-__logf(u));
}

// ---------------------------------------------------------------------------
// Kernel 1: per-row softmax stats + relevance sum. One wave per row.
// ---------------------------------------------------------------------------
__global__ __launch_bounds__(64) void pg_prep_kernel(
    const float* __restrict__ score, const float* __restrict__ rel,
    float4* __restrict__ wsb) {
  const int b = blockIdx.x;
  const int lane = threadIdx.x;  // 0..63
  const float4* s4 = (const float4*)(score + (size_t)b * M_DIM);
  const float4* r4 = (const float4*)(rel + (size_t)b * M_DIM);
  float4 a = s4[lane * 2];
  float4 c = s4[lane * 2 + 1];
  float4 ra = r4[lane * 2];
  float4 rc = r4[lane * 2 + 1];

  float mx = fmaxf(fmaxf(fmaxf(a.x, a.y), fmaxf(a.z, a.w)),
                   fmaxf(fmaxf(c.x, c.y), fmaxf(c.z, c.w)));
#pragma unroll
  for (int off = 32; off > 0; off >>= 1) mx = fmaxf(mx, __shfl_xor(mx, off));

  float se = expf(a.x - mx) + expf(a.y - mx) + expf(a.z - mx) + expf(a.w - mx)
           + expf(c.x - mx) + expf(c.y - mx) + expf(c.z - mx) + expf(c.w - mx);
#pragma unroll
  for (int off = 32; off > 0; off >>= 1) se += __shfl_xor(se, off);

  float sr = ra.x + ra.y + ra.z + ra.w + rc.x + rc.y + rc.z + rc.w;
#pragma unroll
  for (int off = 32; off > 0; off >>= 1) sr += __shfl_xor(sr, off);

  if (lane == 0) wsb[b] = make_float4(mx, logf(se), sr, 0.0f);
}

// ---------------------------------------------------------------------------
// Kernel 2: one wave per (b, s). Gumbel top-10 + set-invariant reward +
// random permutation + Plackett-Luce log-prob. Writes per-wave contribution.
// ---------------------------------------------------------------------------
__global__ __launch_bounds__(WPB * 64) void pg_main_kernel(
    const float* __restrict__ score, const float* __restrict__ rel,
    const float* __restrict__ eth, const float4* __restrict__ wsb,
    float* __restrict__ contrib) {
  const int wave = threadIdx.x >> 6;
  const int lane = threadIdx.x & 63;
  const int wg = blockIdx.x * WPB + wave;  // 0..NWAVES-1
  const int b = wg / NUM_MC;

  const float4 w = wsb[b];
  const float smax = w.x, lse = w.y, sumrel = w.z;

  // lane handles 8 consecutive items m = lane*8 + j (vectorized loads).
  const float4* s4 = (const float4*)(score + (size_t)b * M_DIM);
  float4 a = s4[lane * 2];
  float4 c = s4[lane * 2 + 1];
  float logp[8];
  logp[0] = a.x - smax - lse; logp[1] = a.y - smax - lse;
  logp[2] = a.z - smax - lse; logp[3] = a.w - smax - lse;
  logp[4] = c.x - smax - lse; logp[5] = c.y - smax - lse;
  logp[6] = c.z - smax - lse; logp[7] = c.w - smax - lse;

  // Gumbel-perturbed keys. Counter space (x0=0): wg*512 + m, all distinct.
  float key[8];
  {
    const uint32_t base = ((uint32_t)wg << 9) + (uint32_t)(lane * 8);
#pragma unroll
    for (int t = 0; t < 4; ++t) {
      uint32_t o0, o1;
      tf2x32(RK0, RK1, 0u, base + 2u * (uint32_t)t, o0, o1);
      key[2 * t]     = logp[2 * t]     + gumbel_from_bits(o0);
      key[2 * t + 1] = logp[2 * t + 1] + gumbel_from_bits(o1);
    }
  }

  // Iterative top-10 extraction: local max of 8 + wave butterfly max.
  float top_lp[K_TOP];
  int top_idx[K_TOP];
#pragma unroll
  for (int i = 0; i < K_TOP; ++i) {
    float bv = key[0]; int bj = 0;
#pragma unroll
    for (int j = 1; j < 8; ++j) { if (key[j] > bv) { bv = key[j]; bj = j; } }
    int bi = lane * 8 + bj;
#pragma unroll
    for (int off = 32; off > 0; off >>= 1) {
      float ov = __shfl_xor(bv, off);
      int oi = __shfl_xor(bi, off);
      if (ov > bv || (ov == bv && oi < bi)) { bv = ov; bi = oi; }
    }
    const int oj = bi & 7, ol = bi >> 3;
    float myv = logp[0];
#pragma unroll
    for (int j = 1; j < 8; ++j) { if (oj == j) myv = logp[j]; }
    top_lp[i] = __shfl(myv, ol);
    top_idx[i] = bi;
    if (lane == ol) {
#pragma unroll
      for (int j = 0; j < 8; ++j) { if (j == oj) key[j] = -INFINITY; }
    }
  }

  // ---- set-invariant reward: lanes 0..9 gather relevance + ethics vectors.
  int myidx = 0;
#pragma unroll
  for (int i = 0; i < K_TOP; ++i) { if (lane == i) myidx = top_idx[i]; }
  float r_l = 0.0f;
  float4 ea = make_float4(0.f, 0.f, 0.f, 0.f);
  float4 eb = make_float4(0.f, 0.f, 0.f, 0.f);
  if (lane < K_TOP) {
    r_l = rel[(size_t)b * M_DIM + myidx];
    const float4* e4 =
        (const float4*)(eth + ((size_t)b * M_DIM + (size_t)myidx) * E_DIM);
    ea = e4[0]; eb = e4[1];
  }
  float R10 = r_l;
#pragma unroll
  for (int off = 32; off > 0; off >>= 1) R10 += __shfl_xor(R10, off);
  const float relk = (lane < K_TOP) ? r_l / R10 : 0.0f;
  float d0 = relk * ea.x, d1 = relk * ea.y, d2 = relk * ea.z, d3 = relk * ea.w;
  float d4 = relk * eb.x, d5 = relk * eb.y, d6 = relk * eb.z, d7 = relk * eb.w;
#pragma unroll
  for (int off = 32; off > 0; off >>= 1) {
    d0 += __shfl_xor(d0, off); d1 += __shfl_xor(d1, off);
    d2 += __shfl_xor(d2, off); d3 += __shfl_xor(d3, off);
    d4 += __shfl_xor(d4, off); d5 += __shfl_xor(d5, off);
    d6 += __shfl_xor(d6, off); d7 += __shfl_xor(d7, off);
  }

  __shared__ float pbuf[WPB][K_TOP];
  if (lane == 0) {
    // entropy of pz = delta_f / sum(delta_f)
    const float Z = d0 + d1 + d2 + d3 + d4 + d5 + d6 + d7;
    const float iz = 1.0f / Z;
    float ent = 0.0f;
    ent -= (d0 * iz) * logf(d0 * iz); ent -= (d1 * iz) * logf(d1 * iz);
    ent -= (d2 * iz) * logf(d2 * iz); ent -= (d3 * iz) * logf(d3 * iz);
    ent -= (d4 * iz) * logf(d4 * iz); ent -= (d5 * iz) * logf(d5 * iz);
    ent -= (d6 * iz) * logf(d6 * iz); ent -= (d7 * iz) * logf(d7 * iz);
    // delta = sum_topK rel_n - sum_rest rel_n = 2*(R10/sumrel) - 1
    const float delta = 2.0f * (R10 / sumrel) - 1.0f;
    const float reward = delta + ent;  // LAM = 1

    // uniform random permutation of the top-10 p values (Fisher-Yates).
#pragma unroll
    for (int i = 0; i < K_TOP; ++i) pbuf[wave][i] = expf(top_lp[i]);
    uint32_t rnd[K_TOP];
#pragma unroll
    for (int t = 0; t < 5; ++t) {
      uint32_t o0, o1;
      tf2x32(RK0, RK1, 1u, (uint32_t)(wg * 8 + t), o0, o1);  // x0=1 stream
      rnd[2 * t] = o0; rnd[2 * t + 1] = o1;
    }
#pragma unroll
    for (int i = K_TOP - 1; i >= 1; --i) {
      int j = (int)(rnd[K_TOP - 1 - i] % (uint32_t)(i + 1));
      float tmp = pbuf[wave][i]; pbuf[wave][i] = pbuf[wave][j]; pbuf[wave][j] = tmp;
    }

    // Plackett-Luce log-prob of first K slots: denom_0 = sum(all p) = 1.
    float denom = 1.0f;
    float lp = 15.104412573075516f;  // log(10!)
#pragma unroll
    for (int i = 0; i < K_TOP; ++i) {
      const float v = pbuf[wave][i];
      lp += logf(v) - logf(denom);
      denom -= v;
    }
    contrib[wg] = -lp * reward * (1.0f / (float)NWAVES);
  }
}

// ---------------------------------------------------------------------------
// Kernel 3: deterministic fixed-order reduction of per-wave contributions.
// ---------------------------------------------------------------------------
__global__ __launch_bounds__(256) void pg_reduce_kernel(
    const float* __restrict__ contrib, float* __restrict__ out) {
  __shared__ float red[256];
  float acc = 0.0f;
  for (int i = threadIdx.x; i < NWAVES; i += 256) acc += contrib[i];
  red[threadIdx.x] = acc;
  __syncthreads();
#pragma unroll
  for (int s = 128; s > 0; s >>= 1) {
    if (threadIdx.x < s) red[threadIdx.x] += red[threadIdx.x + s];
    __syncthreads();
  }
  if (threadIdx.x == 0) out[0] = red[0];
}

extern "C" void kernel_launch(void* const* d_in, const int* in_sizes, int n_in,
                              void* d_out, int out_size, void* d_ws, size_t ws_size,
                              hipStream_t stream) {
  const float* score = (const float*)d_in[0];
  const float* rel = (const float*)d_in[1];
  const float* eth = (const float*)d_in[2];
  float* out = (float*)d_out;

  float4* wsb = (float4*)d_ws;                       // B_DIM float4
  float* contrib = (float*)d_ws + 4 * B_DIM;         // NWAVES floats

  hipLaunchKernelGGL(pg_prep_kernel, dim3(B_DIM), dim3(64), 0, stream,
                     score, rel, wsb);
  hipLaunchKernelGGL(pg_main_kernel, dim3(NWAVES / WPB), dim3(WPB * 64), 0,
                     stream, score, rel, eth, (const float4*)wsb, contrib);
  hipLaunchKernelGGL(pg_reduce_kernel, dim3(1), dim3(256), 0, stream,
                     contrib, out);
}

// Round 2
// 140.335 us; speedup vs baseline: 2.0586x; 2.0586x over previous
//
#include <hip/hip_runtime.h>
#include <stdint.h>
#include <math.h>

#define B_DIM 2048
#define M_DIM 512
#define E_DIM 8
#define K_TOP 10
#define NUM_MC 25
#define NWAVES (B_DIM * NUM_MC) /* 51200 waves, one per (b, mc-sample) */
#define WPB 4                   /* waves per block (256 threads) */
#define RED1_BLOCKS 64

// ds_swizzle xor-mode within 32-lane halves (offset must be a literal).
#define SWZF(v, m) __int_as_float(__builtin_amdgcn_ds_swizzle(__float_as_int(v), (((m) << 10) | 0x1f)))
#define SWZU(v, m) ((uint32_t)__builtin_amdgcn_ds_swizzle((int)(v), (((m) << 10) | 0x1f)))

__device__ __forceinline__ uint32_t umax32(uint32_t a, uint32_t b) {
  return a > b ? a : b;
}

// hash-prospector "lowbias32" (2-round). Counter-based; good avalanche on
// sequential counters. ~6 full-rate + 2 quarter-rate ops.
__device__ __forceinline__ uint32_t lowbias32(uint32_t x) {
  x ^= x >> 16; x *= 0x21f0aaadu;
  x ^= x >> 15; x *= 0xd35a2d97u;
  x ^= x >> 15;
  return x;
}

// sum over each 16-lane group (all our contributors live in lanes 0..9).
__device__ __forceinline__ float red16f(float v) {
  v += SWZF(v, 1); v += SWZF(v, 2); v += SWZF(v, 4); v += SWZF(v, 8);
  return v;
}

// ---------------------------------------------------------------------------
// Kernel 1: per-row softmax stats + relevance sum. One wave per row.
// ---------------------------------------------------------------------------
__global__ __launch_bounds__(64) void pg_prep_kernel(
    const float* __restrict__ score, const float* __restrict__ rel,
    float4* __restrict__ wsb) {
  const int b = blockIdx.x;
  const int lane = threadIdx.x;  // 0..63
  const float4* s4 = (const float4*)(score + (size_t)b * M_DIM);
  const float4* r4 = (const float4*)(rel + (size_t)b * M_DIM);
  float4 a = s4[lane * 2];
  float4 c = s4[lane * 2 + 1];
  float4 ra = r4[lane * 2];
  float4 rc = r4[lane * 2 + 1];

  float mx = fmaxf(fmaxf(fmaxf(a.x, a.y), fmaxf(a.z, a.w)),
                   fmaxf(fmaxf(c.x, c.y), fmaxf(c.z, c.w)));
#pragma unroll
  for (int off = 32; off > 0; off >>= 1) mx = fmaxf(mx, __shfl_xor(mx, off));

  float se = __expf(a.x - mx) + __expf(a.y - mx) + __expf(a.z - mx) +
             __expf(a.w - mx) + __expf(c.x - mx) + __expf(c.y - mx) +
             __expf(c.z - mx) + __expf(c.w - mx);
#pragma unroll
  for (int off = 32; off > 0; off >>= 1) se += __shfl_xor(se, off);

  float sr = ra.x + ra.y + ra.z + ra.w + rc.x + rc.y + rc.z + rc.w;
#pragma unroll
  for (int off = 32; off > 0; off >>= 1) sr += __shfl_xor(sr, off);

  if (lane == 0) wsb[b] = make_float4(mx, __logf(se), sr, 0.0f);
}

// ---------------------------------------------------------------------------
// Kernel 2: one wave per (b, s). Gumbel top-10 (packed-key selection) +
// set-invariant reward + parallel permuted Plackett-Luce log-prob.
// ---------------------------------------------------------------------------
__global__ __launch_bounds__(WPB * 64) void pg_main_kernel(
    const float* __restrict__ score, const float* __restrict__ rel,
    const float* __restrict__ eth, const float4* __restrict__ wsb,
    float* __restrict__ contrib) {
  __shared__ float s_logp[WPB][M_DIM];          // 8 KB
  __shared__ float s_ebuf[WPB][K_TOP][E_DIM];   // 1.25 KB
  __shared__ float s_vbuf[WPB][K_TOP];
  __shared__ uint32_t s_rbuf[WPB][K_TOP];

  const int wave = threadIdx.x >> 6;
  const int lane = threadIdx.x & 63;
  const int wg = blockIdx.x * WPB + wave;  // 0..NWAVES-1
  const int b = wg / NUM_MC;

  const float4 w = wsb[b];
  const float nrm = w.x + w.y;  // smax + log-sum-exp
  const float sumrel = w.z;

  // lane handles 8 consecutive items m = lane*8 + j.
  const float4* s4 = (const float4*)(score + (size_t)b * M_DIM);
  float4 a = s4[lane * 2];
  float4 c = s4[lane * 2 + 1];
  float lp[8];
  lp[0] = a.x - nrm; lp[1] = a.y - nrm; lp[2] = a.z - nrm; lp[3] = a.w - nrm;
  lp[4] = c.x - nrm; lp[5] = c.y - nrm; lp[6] = c.z - nrm; lp[7] = c.w - nrm;

  // logp table in LDS (winner lookup is a broadcast ds_read).
  float4* dst = (float4*)&s_logp[wave][lane * 8];
  dst[0] = make_float4(lp[0], lp[1], lp[2], lp[3]);
  dst[1] = make_float4(lp[4], lp[5], lp[6], lp[7]);

  // Gumbel keys, packed monotone: [23-bit key | 9-bit item index].
  uint32_t pk[8];
  const uint32_t cbase = ((uint32_t)wg << 9) + (uint32_t)(lane * 8);
#pragma unroll
  for (int j = 0; j < 8; ++j) {
    uint32_t h = lowbias32(cbase + (uint32_t)j);
    float u = __uint_as_float(0x3f800000u | (h >> 9)) - 1.0f;
    u = fmaxf(u, 1.17549435e-38f);
    float key = lp[j] - __logf(-__logf(u));  // logp + gumbel
    uint32_t ku = __float_as_uint(key);
    uint32_t m = ku ^ (uint32_t)(((int32_t)ku >> 31) | (int32_t)0x80000000);
    pk[j] = (m & 0xFFFFFE00u) | (uint32_t)(lane * 8 + j);
  }

  // Iterative top-10: 7 v_max local, 5 swizzle+max (32-lane halves),
  // 2 readlane + scalar max -> winner uniform in SGPR (free broadcast).
  float top_lp[K_TOP];
  int top_idx[K_TOP];
#pragma unroll
  for (int i = 0; i < K_TOP; ++i) {
    uint32_t v = pk[0];
#pragma unroll
    for (int j = 1; j < 8; ++j) v = umax32(v, pk[j]);
    v = umax32(v, SWZU(v, 1));
    v = umax32(v, SWZU(v, 2));
    v = umax32(v, SWZU(v, 4));
    v = umax32(v, SWZU(v, 8));
    v = umax32(v, SWZU(v, 16));
    uint32_t h0 = (uint32_t)__builtin_amdgcn_readlane((int)v, 0);
    uint32_t h1 = (uint32_t)__builtin_amdgcn_readlane((int)v, 32);
    uint32_t win = h0 > h1 ? h0 : h1;
    int bi = (int)(win & 511u);
    top_idx[i] = bi;
    top_lp[i] = s_logp[wave][bi];  // broadcast read
#pragma unroll
    for (int j = 0; j < 8; ++j) pk[j] = (pk[j] == win) ? 0u : pk[j];
  }

  // ---- set-invariant reward. Lane i (<10) owns top item i.
  int myidx = 0;
  float my_lp = 0.0f;
#pragma unroll
  for (int i = 0; i < K_TOP; ++i) {
    if (lane == i) { myidx = top_idx[i]; my_lp = top_lp[i]; }
  }
  const bool act = (lane < K_TOP);
  const int gidx = act ? myidx : 0;
  float r_l = rel[(size_t)b * M_DIM + gidx];
  const float4* e4 =
      (const float4*)(eth + ((size_t)b * M_DIM + (size_t)gidx) * E_DIM);
  float4 ea = e4[0];
  float4 eb = e4[1];
  r_l = act ? r_l : 0.0f;
  const float R10 = red16f(r_l);  // valid in lanes 0..15
  const float relk = act ? (r_l / R10) : 0.0f;

  if (act) {
    float* row = &s_ebuf[wave][lane][0];
    ((float4*)row)[0] = make_float4(relk * ea.x, relk * ea.y, relk * ea.z, relk * ea.w);
    ((float4*)row)[1] = make_float4(relk * eb.x, relk * eb.y, relk * eb.z, relk * eb.w);
  }
  // transpose: lane j (<8) sums dim j over the 10 rows. Same-wave DS is
  // in-order, no barrier needed.
  const int jcol = lane & 7;
  float d = 0.0f;
#pragma unroll
  for (int k = 0; k < K_TOP; ++k) d += s_ebuf[wave][k][jcol];
  float t = d * __logf(d);
  // pair-reduce (Z, T) over the 8-lane group
  float Z = d, T = t;
  Z += SWZF(Z, 1); T += SWZF(T, 1);
  Z += SWZF(Z, 2); T += SWZF(T, 2);
  Z += SWZF(Z, 4); T += SWZF(T, 4);
  const float ent = __logf(Z) - T / Z;  // -sum pz log pz, valid lanes 0..7

  // ---- permuted Plackett-Luce log-prob, parallel over lanes 0..9.
  // Uniform permutation = ranks of 10 iid random keys.
  const uint32_t rk =
      lowbias32(0x80000000u + ((uint32_t)wg << 4) + (uint32_t)lane);
  const float v_i = __expf(my_lp);
  if (act) {
    s_rbuf[wave][lane] = rk;
    s_vbuf[wave][lane] = v_i;
  }
  float prefix = 0.0f;
#pragma unroll
  for (int j = 0; j < K_TOP; ++j) {
    uint32_t rj = s_rbuf[wave][j];
    float vj = s_vbuf[wave][j];
    bool less = (rj < rk) || (rj == rk && j < lane);
    prefix += less ? vj : 0.0f;
  }
  // my slot's denom = 1 - sum of v's ranked before me; rank-0 term = log1 = 0.
  const float term = __logf(1.0f - prefix);
  float plp = act ? (my_lp - term) : 0.0f;  // sum_i log v_i - log denom_i
  plp = red16f(plp);

  if (lane == 0) {
    const float lp_tot = 15.104412573075516f + plp;  // + log(10!)
    const float delta = 2.0f * (R10 / sumrel) - 1.0f;
    const float reward = delta + ent;  // LAM = 1
    contrib[wg] = -lp_tot * reward * (1.0f / (float)NWAVES);
  }
}

// ---------------------------------------------------------------------------
// Kernel 3a/3b: deterministic two-stage reduction.
// ---------------------------------------------------------------------------
__global__ __launch_bounds__(256) void pg_reduce1(
    const float* __restrict__ contrib, float* __restrict__ partial) {
  const int n = NWAVES / RED1_BLOCKS;  // 800
  const int base = blockIdx.x * n;
  float acc = 0.0f;
  for (int i = threadIdx.x; i < n; i += 256) acc += contrib[base + i];
  __shared__ float red[256];
  red[threadIdx.x] = acc;
  __syncthreads();
#pragma unroll
  for (int s = 128; s > 0; s >>= 1) {
    if (threadIdx.x < s) red[threadIdx.x] += red[threadIdx.x + s];
    __syncthreads();
  }
  if (threadIdx.x == 0) partial[blockIdx.x] = red[0];
}

__global__ __launch_bounds__(64) void pg_reduce2(
    const float* __restrict__ partial, float* __restrict__ out) {
  float v = partial[threadIdx.x];
#pragma unroll
  for (int off = 32; off > 0; off >>= 1) v += __shfl_xor(v, off);
  if (threadIdx.x == 0) out[0] = v;
}

extern "C" void kernel_launch(void* const* d_in, const int* in_sizes, int n_in,
                              void* d_out, int out_size, void* d_ws, size_t ws_size,
                              hipStream_t stream) {
  const float* score = (const float*)d_in[0];
  const float* rel = (const float*)d_in[1];
  const float* eth = (const float*)d_in[2];
  float* out = (float*)d_out;

  float4* wsb = (float4*)d_ws;                        // B_DIM float4
  float* contrib = (float*)d_ws + 4 * B_DIM;          // NWAVES floats
  float* partial = contrib + NWAVES;                  // RED1_BLOCKS floats

  hipLaunchKernelGGL(pg_prep_kernel, dim3(B_DIM), dim3(64), 0, stream,
                     score, rel, wsb);
  hipLaunchKernelGGL(pg_main_kernel, dim3(NWAVES / WPB), dim3(WPB * 64), 0,
                     stream, score, rel, eth, (const float4*)wsb, contrib);
  hipLaunchKernelGGL(pg_reduce1, dim3(RED1_BLOCKS), dim3(256), 0, stream,
                     contrib, partial);
  hipLaunchKernelGGL(pg_reduce2, dim3(1), dim3(64), 0, stream, partial, out);
}